// Round 13
// baseline (25916.003 us; speedup 1.0000x reference)
//
#include <hip/hip_runtime.h>
#include <math.h>

#define TT 2048
#define II 128
#define NN 1024
#define NWG 512        // 128 i-blocks x 4 j-groups
#define NTHR 512

// Swizzle: spreads the 16-float k-windows across all 32 LDS banks.
#define SW(k) ((k) ^ ((((k) >> 5) & 7) << 2))

// Base = R12 (passed, 12.0 ms). Structural delta: tile halved to 8 W-rows/WG
// -> 512 WGs, 2 co-resident WGs/CU (LDS 64 KB each, VGPR ~95 < 128 cap).
// While one WG spins on flags / waits h sc1 loads, the other computes ->
// the ~3.8 us/step serial sync exposure hides under compute. All R12
// machinery (full-index SW swizzle, flag protocol, asm idioms, 2 barriers,
// DPP reduce) kept verbatim; only the tiling/indexing constants change.
// Safety valve: bounded spin (65536) turns a co-residency failure into a
// fast wrong-answer instead of a hang.
//
// Thread map (512 = 64 ksplit x 2 rowgroups x 4 batchgroups):
//   l  = tid[0:6) : k-split, owns k in [16l, 16l+16)
//   rt = tid[6]   : rows n0 = ig*8 + rt*4 .. +4
//   bt = tid[7:9) : batches jg*8 + bt*2 .. +2
// Per thread/step: 4 rows x 2 batches x 16 k = 128 FMA, 24 ds_read_b128.

__device__ __forceinline__ float dpp_add_xor1(float x) {  // quad_perm [1,0,3,2]
    int y = __builtin_amdgcn_update_dpp(0, __float_as_int(x), 0xB1, 0xF, 0xF, true);
    return x + __int_as_float(y);
}
__device__ __forceinline__ float dpp_add_xor2(float x) {  // quad_perm [2,3,0,1]
    int y = __builtin_amdgcn_update_dpp(0, __float_as_int(x), 0x4E, 0xF, 0xF, true);
    return x + __int_as_float(y);
}
__device__ __forceinline__ float dpp_add_xor8(float x) {  // row_ror:8 (xor8 in row16)
    int y = __builtin_amdgcn_update_dpp(0, __float_as_int(x), 0x128, 0xF, 0xF, true);
    return x + __int_as_float(y);
}

__global__ __launch_bounds__(NTHR)
void esn_kernel(const float* __restrict__ u, const float* __restrict__ w_in,
                const float* __restrict__ w, const float* __restrict__ w_bias,
                float* __restrict__ out, unsigned int* __restrict__ flags)
{
    __shared__ alignas(16) float w_lds[8 * 1024];    // 32 KB, swizzled, static
    __shared__ alignas(16) float h_stage[8 * 1024];  // 32 KB, swizzled, per step

    const int tid = threadIdx.x;
    const int wg  = blockIdx.x;
    const int ig  = wg & 127;
    const int jg  = wg >> 7;
    const int l   = tid & 63;
    const int rt  = (tid >> 6) & 1;
    const int bt  = (tid >> 7) & 3;
    const int n0  = ig * 8 + rt * 4;
    const int bgb = jg * 8 + bt * 2;

    // ---- stage W tile (8 rows) into LDS once, swizzled ----
    #pragma unroll
    for (int c = 0; c < 16; ++c) {
        int idx = c * NTHR + tid;        // 0..8191
        int row = idx >> 10;
        int k   = idx & 1023;
        w_lds[row * 1024 + SW(k)] = w[(size_t)(ig * 8 + row) * NN + k];
    }

    // W_in slice (2 floats/row) + bias, in registers
    float2 wir0 = *reinterpret_cast<const float2*>(w_in + (n0 + 0) * II + 2 * l);
    float2 wir1 = *reinterpret_cast<const float2*>(w_in + (n0 + 1) * II + 2 * l);
    float2 wir2 = *reinterpret_cast<const float2*>(w_in + (n0 + 2) * II + 2 * l);
    float2 wir3 = *reinterpret_cast<const float2*>(w_in + (n0 + 3) * II + 2 * l);
    const float b0 = w_bias[n0 + 0];
    const float b1 = w_bias[n0 + 1];
    const float b2 = w_bias[n0 + 2];
    const float b3 = w_bias[n0 + 3];

    // walking pointers (2 batches of u per thread)
    const float* up0 = u + (size_t)(bgb + 0) * TT * II + 2 * l;
    const float* up1 = u + (size_t)(bgb + 1) * TT * II + 2 * l;

    // h staging (identical to R12: 4 float4/thread, full 8 batches x 1024)
    const float *hp0, *hp1, *hp2, *hp3;
    int hw0, hw1, hw2, hw3;
    {
        int f4, bl, k4;
        f4 = 0 * NTHR + tid; bl = f4 >> 8; k4 = f4 & 255;
        hp0 = out + (size_t)(jg * 8 + bl) * TT * NN + 4 * k4 - NN;
        hw0 = bl * 1024 + SW(4 * k4);
        f4 = 1 * NTHR + tid; bl = f4 >> 8; k4 = f4 & 255;
        hp1 = out + (size_t)(jg * 8 + bl) * TT * NN + 4 * k4 - NN;
        hw1 = bl * 1024 + SW(4 * k4);
        f4 = 2 * NTHR + tid; bl = f4 >> 8; k4 = f4 & 255;
        hp2 = out + (size_t)(jg * 8 + bl) * TT * NN + 4 * k4 - NN;
        hw2 = bl * 1024 + SW(4 * k4);
        f4 = 3 * NTHR + tid; bl = f4 >> 8; k4 = f4 & 255;
        hp3 = out + (size_t)(jg * 8 + bl) * TT * NN + 4 * k4 - NN;
        hw3 = bl * 1024 + SW(4 * k4);
    }

    // per-lane swizzled read offsets: SW applied to the FULL index (R6/R9 lesson)
    const int kl = 16 * l;
    const int o0 = SW(kl + 0);
    const int o1 = SW(kl + 4);
    const int o2 = SW(kl + 8);
    const int o3 = SW(kl + 12);
    const int wb = rt * 4 * 1024;    // W row base (4 rows of 8)
    const int hb = bt * 2 * 1024;    // h batch base (2 of 8)

    unsigned int* gflags = flags + jg * 128;

    __syncthreads();   // w_lds ready

    float acc[4][2];

#define DOT(rr, bb, wv, hv) \
    acc[rr][bb] += wv.x*hv.x + wv.y*hv.y + wv.z*hv.z + wv.w*hv.w;

#define QSTEP(o) { \
    float4 wv0 = *reinterpret_cast<const float4*>(&w_lds[wb + 0*1024 + (o)]); \
    float4 wv1 = *reinterpret_cast<const float4*>(&w_lds[wb + 1*1024 + (o)]); \
    float4 wv2 = *reinterpret_cast<const float4*>(&w_lds[wb + 2*1024 + (o)]); \
    float4 wv3 = *reinterpret_cast<const float4*>(&w_lds[wb + 3*1024 + (o)]); \
    float4 hv0 = *reinterpret_cast<const float4*>(&h_stage[hb + 0*1024 + (o)]); \
    float4 hv1 = *reinterpret_cast<const float4*>(&h_stage[hb + 1*1024 + (o)]); \
    DOT(0,0,wv0,hv0) DOT(1,0,wv1,hv0) DOT(2,0,wv2,hv0) DOT(3,0,wv3,hv0) \
    DOT(0,1,wv0,hv1) DOT(1,1,wv1,hv1) DOT(2,1,wv2,hv1) DOT(3,1,wv3,hv1) }

    for (int t = 0; t < TT; ++t) {
        // -- issue u loads (overlap the poll) --
        float2 uv0, uv1;
        asm volatile("global_load_dwordx2 %0, %1, off" : "=v"(uv0) : "v"(up0));
        asm volatile("global_load_dwordx2 %0, %1, off" : "=v"(uv1) : "v"(up1));

        float4 h0, h1, h2, h3;
        if (t > 0) {
            // wait for all 128 producer WGs of this j-group (2 flags/lane)
            const unsigned int tgt = (unsigned)t;
            int spin = 0;
            for (;;) {
                unsigned int v0 = __hip_atomic_load(&gflags[l], __ATOMIC_RELAXED,
                                                    __HIP_MEMORY_SCOPE_AGENT);
                unsigned int v1 = __hip_atomic_load(&gflags[64 + l], __ATOMIC_RELAXED,
                                                    __HIP_MEMORY_SCOPE_AGENT);
                if (__all(((int)(v0 >= tgt)) & ((int)(v1 >= tgt)))) break;
                if (++spin > 65536) break;   // safety valve: garbage beats hang
                __builtin_amdgcn_s_sleep(1);
            }
            asm volatile("" ::: "memory");
            // h_{t-1} -> regs, IC-coherent (sc1)
            asm volatile("global_load_dwordx4 %0, %1, off sc1" : "=v"(h0) : "v"(hp0));
            asm volatile("global_load_dwordx4 %0, %1, off sc1" : "=v"(h1) : "v"(hp1));
            asm volatile("global_load_dwordx4 %0, %1, off sc1" : "=v"(h2) : "v"(hp2));
            asm volatile("global_load_dwordx4 %0, %1, off sc1" : "=v"(h3) : "v"(hp3));
            asm volatile("s_waitcnt vmcnt(4)" ::: "memory");  // u done, h in flight
            __builtin_amdgcn_sched_barrier(0);
        } else {
            asm volatile("s_waitcnt vmcnt(0)" ::: "memory");
            __builtin_amdgcn_sched_barrier(0);
        }

        // -- W_in . u partial (hides h load latency) --
        acc[0][0] = wir0.x * uv0.x + wir0.y * uv0.y;
        acc[1][0] = wir1.x * uv0.x + wir1.y * uv0.y;
        acc[2][0] = wir2.x * uv0.x + wir2.y * uv0.y;
        acc[3][0] = wir3.x * uv0.x + wir3.y * uv0.y;
        acc[0][1] = wir0.x * uv1.x + wir0.y * uv1.y;
        acc[1][1] = wir1.x * uv1.x + wir1.y * uv1.y;
        acc[2][1] = wir2.x * uv1.x + wir2.y * uv1.y;
        acc[3][1] = wir3.x * uv1.x + wir3.y * uv1.y;

        if (t > 0) {
            asm volatile("s_waitcnt vmcnt(0)" ::: "memory");  // h regs ready
            __builtin_amdgcn_sched_barrier(0);
            // (S1a removed: S2 of step t-1 orders prior reads vs these writes)
            *reinterpret_cast<float4*>(&h_stage[hw0]) = h0;
            *reinterpret_cast<float4*>(&h_stage[hw1]) = h1;
            *reinterpret_cast<float4*>(&h_stage[hw2]) = h2;
            *reinterpret_cast<float4*>(&h_stage[hw3]) = h3;
        }
        __syncthreads();   // S1b: h_stage visible to all

        // -- main W.h loop: 24 ds_read_b128 + 128 FMA per thread --
        if (t > 0) {
            QSTEP(o0) QSTEP(o1) QSTEP(o2) QSTEP(o3)
        }

        // -- reduce over lane bits 0..3: DPP (VALU) for xor1/2/8, shfl for 4 --
        #pragma unroll
        for (int rr = 0; rr < 4; ++rr)
            #pragma unroll
            for (int bb = 0; bb < 2; ++bb) {
                float a = acc[rr][bb];
                a = dpp_add_xor1(a);
                a = dpp_add_xor2(a);
                a += __shfl_xor(a, 4);
                a = dpp_add_xor8(a);
                acc[rr][bb] = a;
            }

        // -- select tree: lane l<8 takes output (rr = l&3, bb = (l>>2)&1) --
        const int m = l & 15;
        float c00 = (m & 1) ? acc[1][0] : acc[0][0];
        float c01 = (m & 1) ? acc[3][0] : acc[2][0];
        float c10 = (m & 1) ? acc[1][1] : acc[0][1];
        float c11 = (m & 1) ? acc[3][1] : acc[2][1];
        float d0 = (m & 2) ? c01 : c00;   // acc[m&3][0]
        float d1 = (m & 2) ? c11 : c10;   // acc[m&3][1]
        float v  = (m & 4) ? d1 : d0;     // acc[m&3][(m>>2)&1]
        // sum the four 16-lane k-subgroups
        v += __shfl_xor(v, 16);
        v += __shfl_xor(v, 32);

        if (l < 8) {
            float bs = (m & 2) ? ((m & 1) ? b3 : b2) : ((m & 1) ? b1 : b0);
            int rr = l & 3;
            int bb = (l >> 2) & 1;
            float hval = tanhf(v + bs);
            __hip_atomic_store(out + ((size_t)(bgb + bb) * TT + t) * NN + (n0 + rr),
                               hval, __ATOMIC_RELAXED, __HIP_MEMORY_SCOPE_AGENT);
        }

        asm volatile("s_waitcnt vmcnt(0)" ::: "memory");  // h_t stores durable
        __syncthreads();                                  // S2: WG drained
        if (tid == 0) {
            __hip_atomic_store(&gflags[ig], (unsigned)(t + 1),
                               __ATOMIC_RELAXED, __HIP_MEMORY_SCOPE_AGENT);
        }

        up0 += II; up1 += II;
        hp0 += NN; hp1 += NN; hp2 += NN; hp3 += NN;
    }
#undef DOT
#undef QSTEP
}

extern "C" void kernel_launch(void* const* d_in, const int* in_sizes, int n_in,
                              void* d_out, int out_size, void* d_ws, size_t ws_size,
                              hipStream_t stream) {
    const float* u      = (const float*)d_in[0];
    const float* w_in   = (const float*)d_in[1];
    const float* w      = (const float*)d_in[2];
    const float* w_bias = (const float*)d_in[3];
    float* out          = (float*)d_out;
    unsigned int* flags = (unsigned int*)d_ws;

    // 4 j-groups x 128 flags, zeroed every call (graph-replay safe)
    hipMemsetAsync(flags, 0, 4 * 128 * sizeof(unsigned int), stream);

    // 512 WGs x 512 threads, 64 KB LDS, <=128 VGPR -> exactly 2 WGs/CU, all
    // 512 co-resident; flag spin cannot deadlock (bounded spin regardless).
    esn_kernel<<<dim3(NWG), dim3(NTHR), 0, stream>>>(u, w_in, w, w_bias, out, flags);
}

// Round 15
// 11987.256 us; speedup vs baseline: 2.1620x; 2.1620x over previous
//
#include <hip/hip_runtime.h>
#include <math.h>

#define TT 2048
#define II 128
#define NN 1024
#define NWG 256        // 64 i-blocks x 4 j-groups
#define NTHR 512

// R15: bank-correct swizzle -- the ONLY delta vs R12 (which passed, 12.0 ms).
// b128 LDS ops process 8 lanes/cycle; conflict-freedom must hold within each
// 8-lane group. QSTEP reads at k=16l+4q: new SW gives addr bits[2:4] =
// (q0^l0, q1^l1, l0^l2), bijective over l&7 -> 8 lanes cover all 32 banks.
// R12's (k>>5) variant left bits[2:3]=(q0,q1) constant across the group ->
// 8-way in-group conflicts (5.37e8 stall-cycles measured, ~0.4 us/step).
// Same function on write and read, applied to the FULL index (R6/R9 lesson).
// R14 lesson: bundling deltas (dbuf + per-wave flags + swizzle) re-triggered
// the R8-R11 asm-load spill corruption; this round is single-variable.
#define SW(k) ((k) ^ ((((k) >> 4) & 7) << 2))

__device__ __forceinline__ float dpp_add_xor1(float x) {  // quad_perm [1,0,3,2]
    int y = __builtin_amdgcn_update_dpp(0, __float_as_int(x), 0xB1, 0xF, 0xF, true);
    return x + __int_as_float(y);
}
__device__ __forceinline__ float dpp_add_xor2(float x) {  // quad_perm [2,3,0,1]
    int y = __builtin_amdgcn_update_dpp(0, __float_as_int(x), 0x4E, 0xF, 0xF, true);
    return x + __int_as_float(y);
}
__device__ __forceinline__ float dpp_add_xor8(float x) {  // row_ror:8 (xor8 in row16)
    int y = __builtin_amdgcn_update_dpp(0, __float_as_int(x), 0x128, 0xF, 0xF, true);
    return x + __int_as_float(y);
}

__global__ __launch_bounds__(NTHR)
__attribute__((amdgpu_waves_per_eu(2, 2)))
void esn_kernel(const float* __restrict__ u, const float* __restrict__ w_in,
                const float* __restrict__ w, const float* __restrict__ w_bias,
                float* __restrict__ out, unsigned int* __restrict__ flags)
{
    __shared__ alignas(16) float w_lds[16 * 1024];   // 64 KB, swizzled, static
    __shared__ alignas(16) float h_stage[8 * 1024];  // 32 KB, swizzled, per step

    const int tid = threadIdx.x;
    const int wg  = blockIdx.x;
    const int ig  = wg & 63;
    const int jg  = wg >> 6;
    const int l   = tid & 63;
    const int rt  = (tid >> 6) & 3;
    const int bt  = tid >> 8;            // 0..1
    const int n0  = ig * 16 + rt * 4;
    const int bgb = jg * 8 + bt * 4;

    // ---- stage W tile into LDS once (coalesced global, swizzled LDS) ----
    #pragma unroll
    for (int c = 0; c < 32; ++c) {
        int idx = c * NTHR + tid;        // 0..16383
        int row = idx >> 10;
        int k   = idx & 1023;
        w_lds[row * 1024 + SW(k)] = w[(size_t)(ig * 16 + row) * NN + k];
    }

    // W_in slice (2 floats/row) + bias, in registers
    float2 wir0 = *reinterpret_cast<const float2*>(w_in + (n0 + 0) * II + 2 * l);
    float2 wir1 = *reinterpret_cast<const float2*>(w_in + (n0 + 1) * II + 2 * l);
    float2 wir2 = *reinterpret_cast<const float2*>(w_in + (n0 + 2) * II + 2 * l);
    float2 wir3 = *reinterpret_cast<const float2*>(w_in + (n0 + 3) * II + 2 * l);
    const float b0 = w_bias[n0 + 0];
    const float b1 = w_bias[n0 + 1];
    const float b2 = w_bias[n0 + 2];
    const float b3 = w_bias[n0 + 3];

    // walking pointers
    const float* up0 = u + (size_t)(bgb + 0) * TT * II + 2 * l;
    const float* up1 = u + (size_t)(bgb + 1) * TT * II + 2 * l;
    const float* up2 = u + (size_t)(bgb + 2) * TT * II + 2 * l;
    const float* up3 = u + (size_t)(bgb + 3) * TT * II + 2 * l;

    const float *hp0, *hp1, *hp2, *hp3;
    int hw0, hw1, hw2, hw3;
    {
        int f4, bl, k4;
        f4 = 0 * NTHR + tid; bl = f4 >> 8; k4 = f4 & 255;
        hp0 = out + (size_t)(jg * 8 + bl) * TT * NN + 4 * k4 - NN;
        hw0 = bl * 1024 + SW(4 * k4);
        f4 = 1 * NTHR + tid; bl = f4 >> 8; k4 = f4 & 255;
        hp1 = out + (size_t)(jg * 8 + bl) * TT * NN + 4 * k4 - NN;
        hw1 = bl * 1024 + SW(4 * k4);
        f4 = 2 * NTHR + tid; bl = f4 >> 8; k4 = f4 & 255;
        hp2 = out + (size_t)(jg * 8 + bl) * TT * NN + 4 * k4 - NN;
        hw2 = bl * 1024 + SW(4 * k4);
        f4 = 3 * NTHR + tid; bl = f4 >> 8; k4 = f4 & 255;
        hp3 = out + (size_t)(jg * 8 + bl) * TT * NN + 4 * k4 - NN;
        hw3 = bl * 1024 + SW(4 * k4);
    }

    // per-lane swizzled read offsets: SW applied to the FULL index (R6/R9 lesson)
    const int kl = 16 * l;
    const int o0 = SW(kl + 0);
    const int o1 = SW(kl + 4);
    const int o2 = SW(kl + 8);
    const int o3 = SW(kl + 12);
    const int wb = rt * 4 * 1024;    // row base (k part lives in o0..o3)
    const int hb = bt * 4 * 1024;

    unsigned int* gflags = flags + jg * 64;

    __syncthreads();   // w_lds ready

    float acc[4][4];

#define UPART(bb, uv) \
    acc[0][bb] = wir0.x * uv.x + wir0.y * uv.y; \
    acc[1][bb] = wir1.x * uv.x + wir1.y * uv.y; \
    acc[2][bb] = wir2.x * uv.x + wir2.y * uv.y; \
    acc[3][bb] = wir3.x * uv.x + wir3.y * uv.y;

#define DOT(rr, bb, wv, hv) \
    acc[rr][bb] += wv.x*hv.x + wv.y*hv.y + wv.z*hv.z + wv.w*hv.w;

#define QSTEP(o) { \
    float4 wv0 = *reinterpret_cast<const float4*>(&w_lds[wb + 0*1024 + (o)]); \
    float4 wv1 = *reinterpret_cast<const float4*>(&w_lds[wb + 1*1024 + (o)]); \
    float4 wv2 = *reinterpret_cast<const float4*>(&w_lds[wb + 2*1024 + (o)]); \
    float4 wv3 = *reinterpret_cast<const float4*>(&w_lds[wb + 3*1024 + (o)]); \
    float4 hv0 = *reinterpret_cast<const float4*>(&h_stage[hb + 0*1024 + (o)]); \
    float4 hv1 = *reinterpret_cast<const float4*>(&h_stage[hb + 1*1024 + (o)]); \
    float4 hv2 = *reinterpret_cast<const float4*>(&h_stage[hb + 2*1024 + (o)]); \
    float4 hv3 = *reinterpret_cast<const float4*>(&h_stage[hb + 3*1024 + (o)]); \
    DOT(0,0,wv0,hv0) DOT(1,0,wv1,hv0) DOT(2,0,wv2,hv0) DOT(3,0,wv3,hv0) \
    DOT(0,1,wv0,hv1) DOT(1,1,wv1,hv1) DOT(2,1,wv2,hv1) DOT(3,1,wv3,hv1) \
    DOT(0,2,wv0,hv2) DOT(1,2,wv1,hv2) DOT(2,2,wv2,hv2) DOT(3,2,wv3,hv2) \
    DOT(0,3,wv0,hv3) DOT(1,3,wv1,hv3) DOT(2,3,wv2,hv3) DOT(3,3,wv3,hv3) }

    for (int t = 0; t < TT; ++t) {
        // -- issue u loads (overlap the poll) --
        float2 uv0, uv1, uv2, uv3;
        asm volatile("global_load_dwordx2 %0, %1, off" : "=v"(uv0) : "v"(up0));
        asm volatile("global_load_dwordx2 %0, %1, off" : "=v"(uv1) : "v"(up1));
        asm volatile("global_load_dwordx2 %0, %1, off" : "=v"(uv2) : "v"(up2));
        asm volatile("global_load_dwordx2 %0, %1, off" : "=v"(uv3) : "v"(up3));

        float4 h0, h1, h2, h3;
        if (t > 0) {
            for (;;) {
                unsigned int v = __hip_atomic_load(&gflags[l], __ATOMIC_RELAXED,
                                                   __HIP_MEMORY_SCOPE_AGENT);
                if (__all((int)(v >= (unsigned)t))) break;
                __builtin_amdgcn_s_sleep(1);
            }
            asm volatile("" ::: "memory");
            // h_{t-1} -> regs, IC-coherent (sc1)
            asm volatile("global_load_dwordx4 %0, %1, off sc1" : "=v"(h0) : "v"(hp0));
            asm volatile("global_load_dwordx4 %0, %1, off sc1" : "=v"(h1) : "v"(hp1));
            asm volatile("global_load_dwordx4 %0, %1, off sc1" : "=v"(h2) : "v"(hp2));
            asm volatile("global_load_dwordx4 %0, %1, off sc1" : "=v"(h3) : "v"(hp3));
            asm volatile("s_waitcnt vmcnt(4)" ::: "memory");  // u done, h in flight
            __builtin_amdgcn_sched_barrier(0);
        } else {
            asm volatile("s_waitcnt vmcnt(0)" ::: "memory");
            __builtin_amdgcn_sched_barrier(0);
        }

        // -- W_in . u partial (hides h load latency) --
        UPART(0, uv0) UPART(1, uv1) UPART(2, uv2) UPART(3, uv3)

        if (t > 0) {
            asm volatile("s_waitcnt vmcnt(0)" ::: "memory");  // h regs ready
            __builtin_amdgcn_sched_barrier(0);
            // (S1a removed: S2 of step t-1 orders prior reads vs these writes)
            *reinterpret_cast<float4*>(&h_stage[hw0]) = h0;
            *reinterpret_cast<float4*>(&h_stage[hw1]) = h1;
            *reinterpret_cast<float4*>(&h_stage[hw2]) = h2;
            *reinterpret_cast<float4*>(&h_stage[hw3]) = h3;
        }
        __syncthreads();   // S1b: h_stage visible to all

        // -- main W.h loop: 32 ds_read_b128 + 256 FMA per thread --
        if (t > 0) {
            QSTEP(o0) QSTEP(o1) QSTEP(o2) QSTEP(o3)
        }

        // -- reduce over lane bits 0..3: DPP (VALU) for xor1/2/8, shfl for 4 --
        #pragma unroll
        for (int rr = 0; rr < 4; ++rr)
            #pragma unroll
            for (int bb = 0; bb < 4; ++bb) {
                float a = acc[rr][bb];
                a = dpp_add_xor1(a);
                a = dpp_add_xor2(a);
                a += __shfl_xor(a, 4);
                a = dpp_add_xor8(a);
                acc[rr][bb] = a;
            }

        // -- select tree: lane m (=l&15) takes output (rr = m&3, bb = m>>2) --
        const int m = l & 15;
        float c00 = (m & 1) ? acc[1][0] : acc[0][0];
        float c01 = (m & 1) ? acc[3][0] : acc[2][0];
        float c10 = (m & 1) ? acc[1][1] : acc[0][1];
        float c11 = (m & 1) ? acc[3][1] : acc[2][1];
        float c20 = (m & 1) ? acc[1][2] : acc[0][2];
        float c21 = (m & 1) ? acc[3][2] : acc[2][2];
        float c30 = (m & 1) ? acc[1][3] : acc[0][3];
        float c31 = (m & 1) ? acc[3][3] : acc[2][3];
        float d0 = (m & 2) ? c01 : c00;
        float d1 = (m & 2) ? c11 : c10;
        float d2 = (m & 2) ? c21 : c20;
        float d3 = (m & 2) ? c31 : c30;
        float e0 = (m & 4) ? d1 : d0;
        float e1 = (m & 4) ? d3 : d2;
        float v  = (m & 8) ? e1 : e0;
        // sum the four 16-lane k-subgroups
        v += __shfl_xor(v, 16);
        v += __shfl_xor(v, 32);

        if (l < 16) {
            float bs = (m & 2) ? ((m & 1) ? b3 : b2) : ((m & 1) ? b1 : b0);
            int rr = m & 3;
            int bb = m >> 2;
            float hval = tanhf(v + bs);
            __hip_atomic_store(out + ((size_t)(bgb + bb) * TT + t) * NN + (n0 + rr),
                               hval, __ATOMIC_RELAXED, __HIP_MEMORY_SCOPE_AGENT);
        }

        asm volatile("s_waitcnt vmcnt(0)" ::: "memory");  // h_t stores durable
        __syncthreads();                                  // S2: WG drained
        if (tid == 0) {
            __hip_atomic_store(&gflags[ig], (unsigned)(t + 1),
                               __ATOMIC_RELAXED, __HIP_MEMORY_SCOPE_AGENT);
        }

        up0 += II; up1 += II; up2 += II; up3 += II;
        hp0 += NN; hp1 += NN; hp2 += NN; hp3 += NN;
    }
#undef UPART
#undef DOT
#undef QSTEP
}

extern "C" void kernel_launch(void* const* d_in, const int* in_sizes, int n_in,
                              void* d_out, int out_size, void* d_ws, size_t ws_size,
                              hipStream_t stream) {
    const float* u      = (const float*)d_in[0];
    const float* w_in   = (const float*)d_in[1];
    const float* w      = (const float*)d_in[2];
    const float* w_bias = (const float*)d_in[3];
    float* out          = (float*)d_out;
    unsigned int* flags = (unsigned int*)d_ws;

    hipMemsetAsync(flags, 0, 4 * 64 * sizeof(unsigned int), stream);

    // 256 WGs x 512 threads, 96 KB LDS = exactly 1 WG/CU -> co-residency
    // guaranteed, flag spin cannot deadlock.
    esn_kernel<<<dim3(NWG), dim3(NTHR), 0, stream>>>(u, w_in, w, w_bias, out, flags);
}